// Round 9
// baseline (7615.105 us; speedup 1.0000x reference)
//
#include <hip/hip_runtime.h>
#include <hip/hip_bf16.h>
#include <math.h>

// Problem constants
#define BSZ 64
#define TT  512
#define DD  512
#define UU  512
#define NZ  2048   // 4*U

#define NSL    32    // u-slices (workers per batch group)
#define USL    16    // units per slice
#define NBG    4     // batch groups
#define BG     16    // batches per group (= MFMA m)
#define KSTEPS 16    // 512 / 32 (MFMA k=32)
#define PF     8     // A-load software-pipeline depth
#define SENTW  0xFFFFFFFFu

using short8  = __attribute__((ext_vector_type(8))) short;
using floatx4 = __attribute__((ext_vector_type(4))) float;
typedef unsigned long long u64;

// ---------------------------------------------------------------------------
// Phase 1: zx = x @ Wk.  M=32768, K=512, N=2048. fp32 tiled GEMM (unchanged).
// ---------------------------------------------------------------------------
template <bool ZXBF16>
__global__ __launch_bounds__(256) void gemm_zx(const float* __restrict__ A,
                                               const float* __restrict__ B,
                                               void* __restrict__ Cout) {
  __shared__ float As[16][65];
  __shared__ float Bs[16][64];

  const int tid = threadIdx.x;
  const int tx = tid & 15;
  const int ty = tid >> 4;
  const int m0 = blockIdx.y * 64;
  const int n0 = blockIdx.x * 64;

  const int lm  = tid >> 2;
  const int lk4 = (tid & 3) * 4;
  const int lk  = tid >> 4;
  const int ln4 = (tid & 15) * 4;

  float acc[4][4] = {};

  for (int k0 = 0; k0 < DD; k0 += 16) {
    float4 av = *(const float4*)(A + (size_t)(m0 + lm) * DD + k0 + lk4);
    float4 bv = *(const float4*)(B + (size_t)(k0 + lk) * NZ + n0 + ln4);
    As[lk4 + 0][lm] = av.x;
    As[lk4 + 1][lm] = av.y;
    As[lk4 + 2][lm] = av.z;
    As[lk4 + 3][lm] = av.w;
    *(float4*)&Bs[lk][ln4] = bv;
    __syncthreads();
#pragma unroll
    for (int kk = 0; kk < 16; ++kk) {
      float a[4], b[4];
#pragma unroll
      for (int i = 0; i < 4; ++i) a[i] = As[kk][ty * 4 + i];
#pragma unroll
      for (int j = 0; j < 4; ++j) b[j] = Bs[kk][tx * 4 + j];
#pragma unroll
      for (int i = 0; i < 4; ++i)
#pragma unroll
        for (int j = 0; j < 4; ++j) acc[i][j] = fmaf(a[i], b[j], acc[i][j]);
    }
    __syncthreads();
  }

#pragma unroll
  for (int i = 0; i < 4; ++i) {
    const size_t row = (size_t)(m0 + ty * 4 + i) * NZ + n0 + tx * 4;
    if constexpr (ZXBF16) {
      __hip_bfloat16* C = (__hip_bfloat16*)Cout;
#pragma unroll
      for (int j = 0; j < 4; ++j) C[row + j] = __float2bfloat16(acc[i][j]);
    } else {
      float* C = (float*)Cout;
      *(float4*)&C[row] = make_float4(acc[i][0], acc[i][1], acc[i][2], acc[i][3]);
    }
  }
}

// ---------------------------------------------------------------------------
// Phase 2: persistent kernel, spread layout, per-slice dataflow with
// DATA-AS-FLAG (R8 scheme; R8's failure was a lo-read INDEXING bug, fixed:
// lo fragment = ushort offset +32 = q+8/q+9 in u64 units, NOT q+4/q+5).
//
// Scheme: h planes 1..T pre-filled with sentinel 0xFFFFFFFF (packed bf16
// NaN pair -- unreachable: h = o*tanh(c) and its bf16 remainder are always
// finite; each 32-bit word is written by ONE packed store so no torn
// halves). Consumers poll the h words THEMSELVES with agent-scope relaxed
// 8B atomic loads (IF$-served, same proven mechanism as R0's flags, now
// carrying the payload). word != sentinel => it IS the data, in registers.
//
// Producers: packed 32-bit agent relaxed atomic stores (R0-proven), then a
// RAW s_barrier (no vmcnt drain): stores flow to IF$ in the background;
// consumers detect arrival via sentinels. Per-step serial chain shrinks
// from {drain -> publish -> detect RTT -> load} to {store flight -> poll
// RTT}, overlapped with MFMA by the PF=8 pipeline.
//
// Deadlock impossible: stores unconditional and precede any wait; planes
// write-once, monotone; plane 0 pre-zeroed (0x0 != sentinel).
// ---------------------------------------------------------------------------
__device__ __forceinline__ floatx4 mfma16(short8 a, short8 b, floatx4 c) {
  return __builtin_amdgcn_mfma_f32_16x16x32_bf16(a, b, c, 0, 0, 0);
}

__device__ __forceinline__ u64 aload(const u64* p) {
  return __hip_atomic_load(p, __ATOMIC_RELAXED, __HIP_MEMORY_SCOPE_AGENT);
}
__device__ __forceinline__ bool sbad(u64 v) {
  return ((unsigned)v == SENTW) || ((unsigned)(v >> 32) == SENTW);
}

union S8 {
  short8 s;
  u64 d[2];
};

template <bool ZXBF16>
__global__ __launch_bounds__(256) void lstm_persist(
    const void* __restrict__ zx_, const float* __restrict__ Wr,
    const float* __restrict__ bias, unsigned short* __restrict__ h_c,
    float* __restrict__ out) {
  extern __shared__ char lds[];
  unsigned short* wr_hi = (unsigned short*)lds;            // [K][g][lane][8]
  unsigned short* wr_lo = wr_hi + KSTEPS * 4 * 64 * 8;     // 32768 ushorts each
  float* z_ex = (float*)(wr_lo + KSTEPS * 4 * 64 * 8);     // [4 g][16 b][16 u]

  const int sl = blockIdx.x;          // u-slice 0..31
  const int bg = blockIdx.y;          // batch group 0..3
  const int tid = threadIdx.x;
  const int g = tid >> 6;             // wave = gate 0..3
  const int lane = tid & 63;
  const int u0 = sl * USL;
  const int K0 = sl >> 1;             // cyclic K-loop start = own slice's step

  // ---- one-time: preformat Wr slice into LDS (split bf16, B-frag order) ----
  {
    const int cidx = tid & 63;        // gg*16+u within slice
    const int koff = tid >> 6;        // 0..3
    const int gg = cidx >> 4, u = cidx & 15;
    const int col = gg * UU + u0 + u;
    for (int k0 = 0; k0 < DD; k0 += 4) {
      const int k = k0 + koff;
      const float v = Wr[(size_t)k * NZ + col];
      const __hip_bfloat16 vh = __float2bfloat16(v);
      const float rem = v - __bfloat162float(vh);
      const __hip_bfloat16 vl = __float2bfloat16(rem);
      const int K = k >> 5, kg = (k >> 3) & 3, j = k & 7;
      const int off = ((K * 4 + gg) * 64 + (kg * 16 + u)) * 8 + j;
      wr_hi[off] = *(const unsigned short*)&vh;
      wr_lo[off] = *(const unsigned short*)&vl;
    }
  }
  __syncthreads();

  // MFMA A-fragment addressing: m = bg*16 + (lane&15), kgroup = lane>>4
  const int am = lane & 15, akg = lane >> 4;
  // h layout (ushort idx): ((t*64 + b)*16 + K)*64 + part*32 + (akg*8 + j)
  const size_t arow_c = (size_t)(bg * BG + am) * (KSTEPS * 64) + akg * 8;
  const size_t plane_c = (size_t)BSZ * KSTEPS * 64;  // 65536 ushorts / step

  // epilogue mapping: thread -> (local batch eb, unit eu)
  const int eb = tid >> 4;            // 0..15
  const int eu = tid & 15;            // 0..15
  const int b = bg * BG + eb;         // global batch
  const float bias_i = bias[0 * UU + u0 + eu];
  const float bias_f = bias[1 * UU + u0 + eu];
  const float bias_g = bias[2 * UU + u0 + eu];
  const float bias_o = bias[3 * UU + u0 + eu];
  float c_state = 0.f;
  const int mypair = sl >> 1;
  const int wip = ((sl & 1) * 8) + (eu >> 1);
  const size_t zbase = (size_t)b * TT;

  // ---- zx(t=0) preload (prefetch pipeline primer) ----
  float zi, zf, zg, zo;
  {
    const size_t zb = zbase * NZ + u0 + eu;
    if constexpr (ZXBF16) {
      const unsigned short* zx = (const unsigned short*)zx_;
      zi = __bfloat162float(*(const __hip_bfloat16*)&zx[zb + 0 * UU]);
      zf = __bfloat162float(*(const __hip_bfloat16*)&zx[zb + 1 * UU]);
      zg = __bfloat162float(*(const __hip_bfloat16*)&zx[zb + 2 * UU]);
      zo = __bfloat162float(*(const __hip_bfloat16*)&zx[zb + 3 * UU]);
    } else {
      const float* zx = (const float*)zx_;
      zi = zx[zb + 0 * UU];
      zf = zx[zb + 1 * UU];
      zg = zx[zb + 2 * UU];
      zo = zx[zb + 3 * UU];
    }
  }

  for (int t = 0; t < TT; ++t) {
    const unsigned short* Ab = h_c + (size_t)t * plane_c + arow_c;

    // ---- prologue: issue (unvalidated) A-polls for first PF K-steps ----
    // hi fragment = q[0],q[1] (ushorts 0..7); lo = q[8],q[9] (ushorts 32..39)
    u64 h0[PF], h1[PF], l0[PF], l1[PF];
#pragma unroll
    for (int p = 0; p < PF; ++p) {
      const int K = (K0 + p) & 15;
      const u64* q = (const u64*)(Ab + K * 64);
      h0[p] = aload(q);
      h1[p] = aload(q + 1);
      l0[p] = aload(q + 8);
      l1[p] = aload(q + 9);
    }

    // ---- zx(t+1) register prefetch (independent; hides under MFMA) ----
    float nzi = 0.f, nzf = 0.f, nzg = 0.f, nzo = 0.f;
    if (t + 1 < TT) {
      const size_t zb = (zbase + t + 1) * NZ + u0 + eu;
      if constexpr (ZXBF16) {
        const unsigned short* zx = (const unsigned short*)zx_;
        nzi = __bfloat162float(*(const __hip_bfloat16*)&zx[zb + 0 * UU]);
        nzf = __bfloat162float(*(const __hip_bfloat16*)&zx[zb + 1 * UU]);
        nzg = __bfloat162float(*(const __hip_bfloat16*)&zx[zb + 2 * UU]);
        nzo = __bfloat162float(*(const __hip_bfloat16*)&zx[zb + 3 * UU]);
      } else {
        const float* zx = (const float*)zx_;
        nzi = zx[zb + 0 * UU];
        nzf = zx[zb + 1 * UU];
        nzg = zx[zb + 2 * UU];
        nzo = zx[zb + 3 * UU];
      }
    }

    // ---- steady K-loop: validate slot j, MFMA, prefetch slot j+PF ----
    floatx4 a0 = {0, 0, 0, 0}, a1 = {0, 0, 0, 0}, a2 = {0, 0, 0, 0};
#pragma unroll
    for (int j = 0; j < KSTEPS; ++j) {
      const int s = j & (PF - 1);
      const int K = (K0 + j) & 15;
      const u64* q = (const u64*)(Ab + K * 64);
      // validate: any sentinel word -> reload just those (per-lane divergent)
      while (sbad(h0[s]) | sbad(h1[s]) | sbad(l0[s]) | sbad(l1[s])) {
        if (sbad(h0[s])) h0[s] = aload(q);
        if (sbad(h1[s])) h1[s] = aload(q + 1);
        if (sbad(l0[s])) l0[s] = aload(q + 8);
        if (sbad(l1[s])) l1[s] = aload(q + 9);
      }
      S8 Ah, Al;
      Ah.d[0] = h0[s];
      Ah.d[1] = h1[s];
      Al.d[0] = l0[s];
      Al.d[1] = l1[s];
      if (j + PF < KSTEPS) {
        const int Kp = (K0 + j + PF) & 15;
        const u64* qp = (const u64*)(Ab + Kp * 64);
        h0[s] = aload(qp);
        h1[s] = aload(qp + 1);
        l0[s] = aload(qp + 8);
        l1[s] = aload(qp + 9);
      }
      const short8 bhi = *(const short8*)(wr_hi + ((K * 4 + g) * 64 + lane) * 8);
      const short8 blo = *(const short8*)(wr_lo + ((K * 4 + g) * 64 + lane) * 8);
      a0 = mfma16(Ah.s, bhi, a0);
      a1 = mfma16(Ah.s, blo, a1);
      a2 = mfma16(Al.s, bhi, a2);
    }

    // C layout: u = lane&15, b-in-tile = (lane>>4)*4 + r
#pragma unroll
    for (int r = 0; r < 4; ++r) {
      const int bb = (lane >> 4) * 4 + r;
      z_ex[(g * 16 + bb) * 16 + (lane & 15)] = a0[r] + a1[r] + a2[r];
    }
    __syncthreads();

    // ---- pointwise gates: thread = (eb, eu) ----
    zi += z_ex[(0 * 16 + eb) * 16 + eu] + bias_i;
    zf += z_ex[(1 * 16 + eb) * 16 + eu] + bias_f;
    zg += z_ex[(2 * 16 + eb) * 16 + eu] + bias_g;
    zo += z_ex[(3 * 16 + eb) * 16 + eu] + bias_o;

    const float ig = 1.f / (1.f + expf(-zi));
    const float fg = 1.f / (1.f + expf(-zf));
    const float gg = tanhf(zg);
    const float og = 1.f / (1.f + expf(-zo));
    c_state = fg * c_state + ig * gg;
    const float hn = og * tanhf(c_state);

    // split-bf16; pack pair-words via shfl, even threads store packed 32-bit
    // agent-scope RELAXED atomics (line-exclusive layout). Never equals the
    // sentinel (finite bf16 pairs). No drain, no flag: data IS the flag.
    const __hip_bfloat16 hh = __float2bfloat16(hn);
    const float hrem = hn - __bfloat162float(hh);
    const __hip_bfloat16 hl = __float2bfloat16(hrem);
    const unsigned int vhi = (unsigned int)*(const unsigned short*)&hh;
    const unsigned int vlo = (unsigned int)*(const unsigned short*)&hl;
    const unsigned int phi_n = (unsigned int)__shfl_xor((int)vhi, 1);
    const unsigned int plo_n = (unsigned int)__shfl_xor((int)vlo, 1);
    if ((tid & 1) == 0) {
      const unsigned int whi = vhi | (phi_n << 16);
      const unsigned int wlo = vlo | (plo_n << 16);
      unsigned int* blk = (unsigned int*)h_c +
                          (((size_t)(t + 1) * BSZ + b) * KSTEPS + mypair) * 32;
      __hip_atomic_store(blk + wip, whi, __ATOMIC_RELAXED,
                         __HIP_MEMORY_SCOPE_AGENT);
      __hip_atomic_store(blk + 16 + wip, wlo, __ATOMIC_RELAXED,
                         __HIP_MEMORY_SCOPE_AGENT);
    }

    if (t == TT - 1) out[(size_t)b * UU + u0 + eu] = hn;

    // rotate zx pipeline
    zi = nzi; zf = nzf; zg = nzg; zo = nzo;

    // ---- raw barrier: orders z_ex read-before-rewrite, does NOT drain the
    //      in-flight h stores (consumers detect them via sentinels). ----
    asm volatile("s_barrier" ::: "memory");
  }
}

// ---------------------------------------------------------------------------
extern "C" void kernel_launch(void* const* d_in, const int* in_sizes, int n_in,
                              void* d_out, int out_size, void* d_ws, size_t ws_size,
                              hipStream_t stream) {
  const float* x    = (const float*)d_in[0];
  const float* Wk   = (const float*)d_in[1];
  const float* Wr   = (const float*)d_in[2];
  const float* bias = (const float*)d_in[3];
  float* out = (float*)d_out;

  const size_t plane_bytes = (size_t)BSZ * KSTEPS * 128;         // 131072
  const size_t h_bytes = (size_t)(TT + 1) * plane_bytes;         // 64.1 MiB
  const size_t zx_f32_bytes = (size_t)BSZ * TT * NZ * 4;         // 256 MiB

  const size_t need_f32 = zx_f32_bytes + h_bytes;
  const bool use_bf16_zx = (ws_size < need_f32);
  const size_t zx_bytes = use_bf16_zx ? zx_f32_bytes / 2 : zx_f32_bytes;

  char* ws = (char*)d_ws;
  void* zx = (void*)ws;
  unsigned short* h_c = (unsigned short*)(ws + zx_bytes);

  // plane 0 = h_0 = zeros (0x0 != sentinel => t=0 proceeds immediately);
  // planes 1..TT = sentinel 0xFFFFFFFF (data-as-flag).
  hipMemsetAsync(h_c, 0, plane_bytes, stream);
  hipMemsetAsync((char*)h_c + plane_bytes, 0xFF, (size_t)TT * plane_bytes,
                 stream);

  dim3 ggrid(NZ / 64, (BSZ * TT) / 64);
  if (use_bf16_zx)
    gemm_zx<true><<<ggrid, 256, 0, stream>>>(x, Wk, zx);
  else
    gemm_zx<false><<<ggrid, 256, 0, stream>>>(x, Wk, zx);

  const int lds_bytes = KSTEPS * 4 * 64 * 8 * 2 * 2 + 4 * 16 * 16 * 4;  // 135168
  dim3 pgrid(NSL, NBG);  // spread layout
  if (use_bf16_zx) {
    hipFuncSetAttribute(reinterpret_cast<const void*>(lstm_persist<true>),
                        hipFuncAttributeMaxDynamicSharedMemorySize, lds_bytes);
    lstm_persist<true><<<pgrid, 256, lds_bytes, stream>>>(zx, Wr, bias, h_c,
                                                          out);
  } else {
    hipFuncSetAttribute(reinterpret_cast<const void*>(lstm_persist<false>),
                        hipFuncAttributeMaxDynamicSharedMemorySize, lds_bytes);
    lstm_persist<false><<<pgrid, 256, lds_bytes, stream>>>(zx, Wr, bias, h_c,
                                                           out);
  }
}

// Round 10
// 3671.133 us; speedup vs baseline: 2.0743x; 2.0743x over previous
//
#include <hip/hip_runtime.h>
#include <hip/hip_bf16.h>
#include <math.h>

// Problem constants
#define BSZ 64
#define TT  512
#define DD  512
#define UU  512
#define NZ  2048   // 4*U

#define NSL    32    // u-slices
#define USL    16    // units per slice
#define NBG    4     // batch groups
#define BG     16    // batches per group (= MFMA m)
#define KSTEPS 16    // 512 / 32 (MFMA k=32)

using short8  = __attribute__((ext_vector_type(8))) short;
using floatx4 = __attribute__((ext_vector_type(4))) float;
typedef unsigned long long u64;

__device__ __forceinline__ floatx4 mfma16(short8 a, short8 b, floatx4 c) {
  return __builtin_amdgcn_mfma_f32_16x16x32_bf16(a, b, c, 0, 0, 0);
}

// ---------------------------------------------------------------------------
// Conversion pass 1: x (fp32 [M=32768][K=512], k contiguous) -> bf16, same
// layout. 8 elems/thread, short8 stores. Aliased into the h_hi slab (read
// only during the gemm; h plane0 memset happens after the gemm).
// ---------------------------------------------------------------------------
__global__ __launch_bounds__(256) void conv_x(const float* __restrict__ x,
                                              unsigned short* __restrict__ xb) {
  const size_t base = ((size_t)blockIdx.x * 256 + threadIdx.x) * 8;
  float4 a = *(const float4*)(x + base);
  float4 b = *(const float4*)(x + base + 4);
  short8 v;
  const float va[8] = {a.x, a.y, a.z, a.w, b.x, b.y, b.z, b.w};
#pragma unroll
  for (int i = 0; i < 8; ++i) {
    __hip_bfloat16 h = __float2bfloat16(va[i]);
    v[i] = *(const short*)&h;
  }
  *(short8*)(xb + base) = v;
}

// ---------------------------------------------------------------------------
// Conversion pass 2: Wk (fp32 [K=512][N=2048]) -> WkT bf16 [N][K] (transposed
// so B-fragments read 8 contiguous k). Coalesced reads (256 consecutive n per
// j); each thread packs 8 k into one short8 store. Aliased into h_lo slab.
// grid (8, 64): n = bx*256+tid, k0 = by*8.
// ---------------------------------------------------------------------------
__global__ __launch_bounds__(256) void conv_wkt(const float* __restrict__ Wk,
                                                unsigned short* __restrict__ wkt) {
  const int n = blockIdx.x * 256 + threadIdx.x;
  const int k0 = blockIdx.y * 8;
  short8 v;
#pragma unroll
  for (int j = 0; j < 8; ++j) {
    __hip_bfloat16 h = __float2bfloat16(Wk[(size_t)(k0 + j) * NZ + n]);
    v[j] = *(const short*)&h;
  }
  *(short8*)(wkt + (size_t)n * DD + k0) = v;
}

// ---------------------------------------------------------------------------
// Phase 1: zx = x @ Wk via bf16 MFMA. M=32768, K=512, N=2048.
// Tile 64x64, BK=32, 4 waves (wave w = m-strip w*16..+16). Fragment
// conventions identical to the (proven) persist kernel:
//   A-frag: lane -> m=lane&15, kg=lane>>4, elems j -> A[m][kg*8+j]
//   B-frag: lane=kg*16+u -> B[k=kg*8+j][u]  (from WkT[n][k], contiguous k)
//   C:      col=lane&15, row=(lane>>4)*4+r
// LDS stride 40 ushorts (80 B, 16B-multiple for b128; 2-way bank alias only).
// Single-bf16 (no hi/lo split): error budget analyzed, ~2x current zx error.
// ---------------------------------------------------------------------------
__global__ __launch_bounds__(256) void gemm_zx_mfma(
    const unsigned short* __restrict__ xb, const unsigned short* __restrict__ wkt,
    __hip_bfloat16* __restrict__ C) {
  __shared__ unsigned short As[64 * 40];
  __shared__ unsigned short Bs[64 * 40];

  const int tid = threadIdx.x;
  const int w = tid >> 6;
  const int lane = tid & 63;
  const int n0 = blockIdx.x * 64;
  const int m0 = blockIdx.y * 64;

  const int srow = tid >> 2;          // 0..63
  const int skq = tid & 3;            // 0..3 -> k-offset skq*8

  const int fm = (w * 16 + (lane & 15)) * 40 + (lane >> 4) * 8;  // A-frag idx
  const int fu = (lane & 15) * 40 + (lane >> 4) * 8;             // B-frag base

  floatx4 acc[4] = {{0, 0, 0, 0}, {0, 0, 0, 0}, {0, 0, 0, 0}, {0, 0, 0, 0}};

  for (int k0 = 0; k0 < DD; k0 += 32) {
    const short8 av = *(const short8*)(xb + (size_t)(m0 + srow) * DD + k0 + skq * 8);
    const short8 bv = *(const short8*)(wkt + (size_t)(n0 + srow) * DD + k0 + skq * 8);
    *(short8*)&As[srow * 40 + skq * 8] = av;
    *(short8*)&Bs[srow * 40 + skq * 8] = bv;
    __syncthreads();
    const short8 Af = *(const short8*)&As[fm];
#pragma unroll
    for (int ns = 0; ns < 4; ++ns) {
      const short8 Bf = *(const short8*)&Bs[ns * 16 * 40 + fu];
      acc[ns] = mfma16(Af, Bf, acc[ns]);
    }
    __syncthreads();
  }

  const int erow = m0 + w * 16 + (lane >> 4) * 4;
  const int ecol = n0 + (lane & 15);
#pragma unroll
  for (int ns = 0; ns < 4; ++ns)
#pragma unroll
    for (int r = 0; r < 4; ++r)
      C[(size_t)(erow + r) * NZ + ecol + ns * 16] = __float2bfloat16(acc[ns][r]);
}

// ---------------------------------------------------------------------------
// Phase 2: persistent LSTM kernel -- BYTE-IDENTICAL to R0 (best measured:
// 3525us). Spread layout (NSL x NBG blocks), split-bf16 Wr MFMA, 32
// agent-scope flags + tid<NSL poll rendezvous. See R0 notes.
// ---------------------------------------------------------------------------
template <bool ZXBF16>
__global__ __launch_bounds__(256) void lstm_persist(
    const void* __restrict__ zx_, const float* __restrict__ Wr,
    const float* __restrict__ bias, unsigned short* __restrict__ h_hi,
    unsigned short* __restrict__ h_lo, int* __restrict__ flags,
    float* __restrict__ out) {
  extern __shared__ char lds[];
  unsigned short* wr_hi = (unsigned short*)lds;            // [K][g][lane][8]
  unsigned short* wr_lo = wr_hi + KSTEPS * 4 * 64 * 8;     // 32768 ushorts each
  float* z_ex = (float*)(wr_lo + KSTEPS * 4 * 64 * 8);     // [4 g][16 b][16 u]

  const int sl = blockIdx.x;          // u-slice 0..31
  const int bg = blockIdx.y;          // batch group 0..3
  const int tid = threadIdx.x;
  const int g = tid >> 6;             // wave = gate 0..3
  const int lane = tid & 63;
  const int u0 = sl * USL;

  // ---- one-time: preformat Wr slice into LDS (split bf16, B-frag order) ----
  {
    const int cidx = tid & 63;        // gg*16+u within slice
    const int koff = tid >> 6;        // 0..3
    const int gg = cidx >> 4, u = cidx & 15;
    const int col = gg * UU + u0 + u;
    for (int k0 = 0; k0 < DD; k0 += 4) {
      const int k = k0 + koff;
      const float v = Wr[(size_t)k * NZ + col];
      const __hip_bfloat16 vh = __float2bfloat16(v);
      const float rem = v - __bfloat162float(vh);
      const __hip_bfloat16 vl = __float2bfloat16(rem);
      const int K = k >> 5, kg = (k >> 3) & 3, j = k & 7;
      const int off = ((K * 4 + gg) * 64 + (kg * 16 + u)) * 8 + j;
      wr_hi[off] = *(const unsigned short*)&vh;
      wr_lo[off] = *(const unsigned short*)&vl;
    }
  }
  __syncthreads();

  // MFMA A-fragment addressing: m = bg*16 + (lane&15), kgroup = lane>>4
  const int am = lane & 15, akg = lane >> 4;
  const size_t arow = (size_t)(bg * BG + am) * UU + akg * 8;  // ushort idx

  // epilogue mapping: thread -> (local batch eb, unit eu)
  const int eb = tid >> 4;            // 0..15
  const int eu = tid & 15;            // 0..15
  const int b = bg * BG + eb;         // global batch
  const float bias_i = bias[0 * UU + u0 + eu];
  const float bias_f = bias[1 * UU + u0 + eu];
  const float bias_g = bias[2 * UU + u0 + eu];
  const float bias_o = bias[3 * UU + u0 + eu];
  float c_state = 0.f;
  const size_t plane_t = (size_t)BSZ * UU;          // 32768 ushorts / timestep
  // packed-pair word index for (b, eu even): (b*UU + u0 + eu)/2
  const int wword = (b * UU + u0 + eu) >> 1;

  int* myflag = flags + (bg * NSL + sl) * 16;

  for (int t = 0; t < TT; ++t) {
    // ---- zx prefetch for this step (independent of h_t) ----
    float zi, zf, zg, zo;
    {
      const size_t zb = ((size_t)b * TT + t) * NZ + u0 + eu;
      if constexpr (ZXBF16) {
        const unsigned short* zx = (const unsigned short*)zx_;
        zi = __bfloat162float(*(const __hip_bfloat16*)&zx[zb + 0 * UU]);
        zf = __bfloat162float(*(const __hip_bfloat16*)&zx[zb + 1 * UU]);
        zg = __bfloat162float(*(const __hip_bfloat16*)&zx[zb + 2 * UU]);
        zo = __bfloat162float(*(const __hip_bfloat16*)&zx[zb + 3 * UU]);
      } else {
        const float* zx = (const float*)zx_;
        zi = zx[zb + 0 * UU];
        zf = zx[zb + 1 * UU];
        zg = zx[zb + 2 * UU];
        zo = zx[zb + 3 * UU];
      }
    }

    // ---- acquire h_t: relaxed poll of this bg's 32 flags, then wg fence ----
    if (tid < NSL) {
      const int* fp = flags + (bg * NSL + tid) * 16;
      while (__hip_atomic_load(fp, __ATOMIC_RELAXED, __HIP_MEMORY_SCOPE_AGENT) < t) {
      }
    }
    __syncthreads();
    __builtin_amdgcn_fence(__ATOMIC_ACQUIRE, "workgroup");

    // ---- z[16b][16u] for gate g via split-bf16 MFMA ----
    const unsigned short* Ahi = h_hi + (size_t)t * plane_t + arow;
    const unsigned short* Alo = h_lo + (size_t)t * plane_t + arow;
    floatx4 a0 = {0, 0, 0, 0}, a1 = {0, 0, 0, 0}, a2 = {0, 0, 0, 0};
#pragma unroll 4
    for (int K = 0; K < KSTEPS; ++K) {
      const short8 ahi = *(const short8*)(Ahi + K * 32);
      const short8 alo = *(const short8*)(Alo + K * 32);
      const short8 bhi = *(const short8*)(wr_hi + ((K * 4 + g) * 64 + lane) * 8);
      const short8 blo = *(const short8*)(wr_lo + ((K * 4 + g) * 64 + lane) * 8);
      a0 = mfma16(ahi, bhi, a0);
      a1 = mfma16(ahi, blo, a1);
      a2 = mfma16(alo, bhi, a2);
    }
    // C layout: u = lane&15, b-in-tile = (lane>>4)*4 + r
#pragma unroll
    for (int r = 0; r < 4; ++r) {
      const int bb = (lane >> 4) * 4 + r;
      z_ex[(g * 16 + bb) * 16 + (lane & 15)] = a0[r] + a1[r] + a2[r];
    }
    __syncthreads();

    // ---- pointwise gates: thread = (eb, eu) ----
    zi += z_ex[(0 * 16 + eb) * 16 + eu] + bias_i;
    zf += z_ex[(1 * 16 + eb) * 16 + eu] + bias_f;
    zg += z_ex[(2 * 16 + eb) * 16 + eu] + bias_g;
    zo += z_ex[(3 * 16 + eb) * 16 + eu] + bias_o;

    const float ig = 1.f / (1.f + expf(-zi));
    const float fg = 1.f / (1.f + expf(-zf));
    const float gg = tanhf(zg);
    const float og = 1.f / (1.f + expf(-zo));
    c_state = fg * c_state + ig * gg;
    const float hn = og * tanhf(c_state);

    // split-bf16; pack pair-words via shfl, even threads store (32-bit atomics)
    const __hip_bfloat16 hh = __float2bfloat16(hn);
    const float hrem = hn - __bfloat162float(hh);
    const __hip_bfloat16 hl = __float2bfloat16(hrem);
    const unsigned int vhi = (unsigned int)*(const unsigned short*)&hh;
    const unsigned int vlo = (unsigned int)*(const unsigned short*)&hl;
    const unsigned int phi_n = (unsigned int)__shfl_xor((int)vhi, 1);
    const unsigned int plo_n = (unsigned int)__shfl_xor((int)vlo, 1);
    if ((tid & 1) == 0) {
      const unsigned int whi = vhi | (phi_n << 16);
      const unsigned int wlo = vlo | (plo_n << 16);
      unsigned int* phi = (unsigned int*)(h_hi + (size_t)(t + 1) * plane_t) + wword;
      unsigned int* plo = (unsigned int*)(h_lo + (size_t)(t + 1) * plane_t) + wword;
      __hip_atomic_store(phi, whi, __ATOMIC_RELAXED, __HIP_MEMORY_SCOPE_AGENT);
      __hip_atomic_store(plo, wlo, __ATOMIC_RELAXED, __HIP_MEMORY_SCOPE_AGENT);
    }

    if (t == TT - 1) out[(size_t)b * UU + u0 + eu] = hn;

    // ---- release: barrier drains vmcnt (stores at coherence point) ----
    __syncthreads();
    if (tid == 0)
      __hip_atomic_store(myflag, t + 1, __ATOMIC_RELAXED,
                         __HIP_MEMORY_SCOPE_AGENT);
  }
}

// ---------------------------------------------------------------------------
extern "C" void kernel_launch(void* const* d_in, const int* in_sizes, int n_in,
                              void* d_out, int out_size, void* d_ws, size_t ws_size,
                              hipStream_t stream) {
  const float* x    = (const float*)d_in[0];
  const float* Wk   = (const float*)d_in[1];
  const float* Wr   = (const float*)d_in[2];
  const float* bias = (const float*)d_in[3];
  float* out = (float*)d_out;

  const size_t plane_t = (size_t)BSZ * UU;                      // 32768
  const size_t hplane_bytes = (size_t)(TT + 1) * plane_t * 2;   // 32.06 MiB
  const size_t flags_bytes = (size_t)NBG * NSL * 16 * 4;        // 8 KiB
  const size_t zx_bytes = (size_t)BSZ * TT * NZ * 2;            // 128 MiB (bf16)

  char* ws = (char*)d_ws;
  __hip_bfloat16* zx = (__hip_bfloat16*)ws;
  unsigned short* h_hi = (unsigned short*)(ws + zx_bytes);
  unsigned short* h_lo = (unsigned short*)(ws + zx_bytes + hplane_bytes);
  int* flags = (int*)(ws + zx_bytes + 2 * hplane_bytes);

  // Conversion buffers ALIAS the h slabs (x_bf16 = 32 MiB <= 32.06 MiB slab;
  // WkT = 2 MiB). They are dead after the gemm; the h_0/flags memsets are
  // ordered AFTER the gemm on the same stream.
  unsigned short* x_bf16 = h_hi;
  unsigned short* wkt    = h_lo;

  // 1) convert inputs to bf16 (WkT transposed for contiguous-k B-frags)
  conv_x<<<dim3((BSZ * TT * DD) / (256 * 8)), 256, 0, stream>>>(x, x_bf16);
  conv_wkt<<<dim3(NZ / 256, DD / 8), 256, 0, stream>>>(Wk, wkt);

  // 2) zx = x @ Wk via bf16 MFMA
  gemm_zx_mfma<<<dim3(NZ / 64, (BSZ * TT) / 64), 256, 0, stream>>>(x_bf16, wkt,
                                                                   zx);

  // 3) init h_0 plane + flags (after the gemm: conv buffers now dead)
  hipMemsetAsync(h_hi, 0, plane_t * 2, stream);
  hipMemsetAsync(h_lo, 0, plane_t * 2, stream);
  hipMemsetAsync(flags, 0, flags_bytes, stream);

  // 4) persistent LSTM (R0 config, unchanged)
  const int lds_bytes = KSTEPS * 4 * 64 * 8 * 2 * 2 + 4 * 16 * 16 * 4;  // 135168
  dim3 pgrid(NSL, NBG);
  hipFuncSetAttribute(reinterpret_cast<const void*>(lstm_persist<true>),
                      hipFuncAttributeMaxDynamicSharedMemorySize, lds_bytes);
  lstm_persist<true><<<pgrid, 256, lds_bytes, stream>>>(zx, Wr, bias, h_hi, h_lo,
                                                        flags, out);
}